// Round 14
// baseline (515.920 us; speedup 1.0000x reference)
//
#include <hip/hip_runtime.h>
#include <hip/hip_bf16.h>
#include <math.h>

// Problem constants
#define B_    64
#define T_    13
#define N_    325
#define H_    64
#define C_    4
#define L_    2
#define S_    4
#define P_    12
#define M_    (B_*N_)      // 20800 (= 1300*16 exactly)
#define ADJLD 1300         // leading dim of combined adjacency inputs
#define NNZCAP 64          // max nonzeros per adjacency row (3% density -> mean ~10)
#define WPITCH 72          // ushort pitch for transposed W tiles (144B rows, 16B-aligned frags)
#define MTP   264          // ushort pitch for 256-wide bf16 tiles (conflict-free)
#define RTP   264          // ushort pitch for transposed reduce_w
#define NBLK  1300         // fused-mix blocks (16 rows each)
#define MIXG  1304         // mix grid (8-swizzle over 1300 + 4 dead)

typedef short bfrag __attribute__((ext_vector_type(8)));   // 8 bf16 = 4 VGPRs
typedef float f32x4 __attribute__((ext_vector_type(4)));

__device__ __forceinline__ void fma4(float4& a, float s, float4 x) {
    a.x += s * x.x; a.y += s * x.y; a.z += s * x.z; a.w += s * x.w;
}
// bf16 pack (RNE) / unpack helpers
__device__ __forceinline__ ushort bf_rne(float f) {
    unsigned u = __float_as_uint(f);
    return (ushort)((u + 0x7fffu + ((u >> 16) & 1u)) >> 16);
}
__device__ __forceinline__ uint2 pack_bf4(float4 v) {
    unsigned a = __float_as_uint(v.x), b = __float_as_uint(v.y);
    unsigned c = __float_as_uint(v.z), d = __float_as_uint(v.w);
    a = (a + 0x7fffu + ((a >> 16) & 1u)) >> 16;
    b = (b + 0x7fffu + ((b >> 16) & 1u)) >> 16;
    c = (c + 0x7fffu + ((c >> 16) & 1u)) >> 16;
    d = (d + 0x7fffu + ((d >> 16) & 1u)) >> 16;
    return make_uint2(a | (b << 16), c | (d << 16));
}
__device__ __forceinline__ float4 unpack_bf4(uint2 p) {
    return make_float4(__uint_as_float(p.x << 16),
                       __uint_as_float(p.x & 0xffff0000u),
                       __uint_as_float(p.y << 16),
                       __uint_as_float(p.y & 0xffff0000u));
}

// ---------------------------------------------------------------------------
// K_SETUP: one dispatch for all independent prep work. Also zeros the 8-float
// LN accumulator array (asum[it][2], it=0..3).
__global__ void k_setup(
    const float* __restrict__ adj_fwd, const float* __restrict__ pea_fwd,
    const float* __restrict__ gadj_w, const float* __restrict__ gpea_w,
    const float* __restrict__ reduce_w,
    const float* __restrict__ gate1_w, const float* __restrict__ gate2_w,
    int* __restrict__ cnt, int* __restrict__ cols, float* __restrict__ vals,
    ushort* __restrict__ WT,
    ushort* __restrict__ RT, ushort* __restrict__ W1T, ushort* __restrict__ W2T,
    float* __restrict__ asum)
{
    int bid = blockIdx.x, t = threadIdx.x;
    if (bid < 163) {
        // ---- sparse build: row = bid*4 + wave; padded, column-ordered ----
        int lane = t & 63, w = t >> 6;
        int row = bid * 4 + w;
        if (row >= 2 * N_) return;
        int mat = (row >= N_) ? 1 : 0;
        int n   = row - mat * N_;
        const float* A = mat ? pea_fwd : adj_fwd;
        const float* rp = A + (size_t)n * ADJLD;
        int* cw   = cols + (size_t)row * NNZCAP;
        float* vw = vals + (size_t)row * NNZCAP;
        int c = 0;
        for (int c0 = 0; c0 < 384; c0 += 64) {
            int col = c0 + lane;
            float v = (col < N_) ? rp[col] : 0.f;
            unsigned long long mmask = __ballot(v != 0.f);
            int idx = c + __popcll(mmask & ((1ull << lane) - 1ull));
            if (v != 0.f && idx < NNZCAP) { cw[idx] = col; vw[idx] = v; }
            c += __popcll(mmask);
        }
        if (c + lane < NNZCAP) { cw[c + lane] = 0; vw[c + lane] = 0.f; }
        if (lane == 0) cnt[row] = (c < NNZCAP) ? c : NNZCAP;
    } else if (bid == 163) {
        // ---- reduce_w [256][64] -> RT[64][RTP] bf16; zero LN accumulators ----
        if (t < 8) asum[t] = 0.f;
        for (int i = 0; i < 64; ++i) {
            int e = t + i * 256;              // e = k*64 + n
            int k = e >> 6, n = e & 63;
            RT[(size_t)n * RTP + k] = bf_rne(reduce_w[e]);
        }
    } else if (bid < 180) {
        // ---- W01-sum transpose: WT[mat][n][k] = W0[k][n]+W1[k][n] ----
        int mat = bid - 164;                  // 0..15
        int layer = mat >> 3, sm = mat & 7;
        int stack = sm >> 2, c = sm & 3;
        const float* w0 = (stack ? gpea_w : gadj_w) + (size_t)((c * L_ + layer) * 2) * 4096;
        const float* w1 = w0 + 4096;
        for (int i = 0; i < 16; ++i) {
            int e = t + i * 256;              // e = k*64 + n
            int k = e >> 6, n = e & 63;
            WT[((size_t)mat * 64 + n) * WPITCH + k] = bf_rne(w0[e] + w1[e]);
        }
    } else if (bid == 180) {
        for (int i = 0; i < 16; ++i) {        // gate W1 64x64
            int e = t + i * 256;
            int k = e >> 6, n = e & 63;
            W1T[(size_t)n * WPITCH + k] = bf_rne(gate1_w[e]);
        }
    } else {
        for (int i = 0; i < 64; ++i) {        // gate W2 64x256
            int e = t + i * 256;
            int k = e >> 8, n = e & 255;
            W2T[(size_t)n * WPITCH + k] = bf_rne(gate2_w[e]);
        }
    }
}

// ---------------------------------------------------------------------------
// Layer-1 block body: 32 rows, both stacks, one checkpoint.
// RANK-3 GATHER: sum_j v_j * g_init[c_j] = s0*w_in[0,:] + s1*w_in[1,:] + sv*b_in
// 8B load per nonzero; 1-ahead metadata rotation.
__device__ __forceinline__ void l1_block(
    int vb, int t, int tt,
    const int*   __restrict__ cnt,
    const int*   __restrict__ cols,
    const float* __restrict__ vals,
    const float* __restrict__ inp,
    const float* __restrict__ w_in, const float* __restrict__ b_in,
    const ushort* __restrict__ WT,
    const float* __restrict__ badj, const float* __restrict__ bpea,
    ushort* __restrict__ G1a, ushort* __restrict__ G1p,
    ushort* MaH, ushort* MpH)         // 32*WPITCH ushorts each
{
    int lane = t & 63, w = t >> 6;
    int m0 = vb * 32;
    int q = lane >> 4, ml = lane & 15;
    int colg = w * 16 + ml;               // this wave-lane's output column

    // prefetch all 16 B-fragments (overlaps gather; WT is L2-resident)
    bfrag BF[8][2];
    #pragma unroll
    for (int mat = 0; mat < 8; ++mat)
        #pragma unroll
        for (int kc = 0; kc < 2; ++kc)
            BF[mat][kc] = *(const bfrag*)&WT[((size_t)mat * 64 + colg) * WPITCH + kc * 32 + q * 8];

    // ---- rank-3 gather (1-ahead rotation) ----
    {
        int row_l  = lane & 7;
        int stackl = (lane >> 3) & 1;
        int part   = lane >> 4;
        int m = m0 + w * 8 + row_l;
        int b = m / N_;
        int n = m - b * N_;
        const float* ipb = inp + ((size_t)(b * T_ + tt) * N_) * 2;
        int rowidx = stackl * N_ + n;
        const int*   cp = cols + (size_t)rowidx * NNZCAP;
        const float* vp = vals + (size_t)rowidx * NNZCAP;
        int myc = cnt[rowidx];
        float s0 = 0.f, s1 = 0.f, sv = 0.f;
        int   cn = cp[part];
        float vn = vp[part];
        for (int j = part; j < myc; j += 4) {
            int   c = cn;
            float v = vn;
            cn = cp[j + 4];               // prefetch (pad/next-row read: discarded)
            vn = vp[j + 4];
            float2 x = *(const float2*)&ipb[(size_t)c * 2];
            s0 += v * x.x; s1 += v * x.y; sv += v;
        }
        // butterfly over part bits (lane bits 4,5)
        s0 += __shfl_xor(s0, 16); s1 += __shfl_xor(s1, 16); sv += __shfl_xor(sv, 16);
        s0 += __shfl_xor(s0, 32); s1 += __shfl_xor(s1, 32); sv += __shfl_xor(sv, 32);
        // expansion: lane = column h; rows w*8..w*8+7, both stacks
        float wa = w_in[lane], wb = w_in[H_ + lane], bi = b_in[lane];
        #pragma unroll
        for (int r = 0; r < 8; ++r) {
            float a0 = __shfl(s0, r),     a1 = __shfl(s1, r),     av = __shfl(sv, r);
            float p0 = __shfl(s0, 8 + r), p1 = __shfl(s1, 8 + r), pv = __shfl(sv, 8 + r);
            MaH[(w * 8 + r) * WPITCH + lane] = bf_rne(a0 * wa + a1 * wb + av * bi);
            MpH[(w * 8 + r) * WPITCH + lane] = bf_rne(p0 * wa + p1 * wb + pv * bi);
        }
    }
    __syncthreads();

    // ---- 8 stages x 2 rowgroups, MFMA; C-layout col=ml, row=q*4+j ----
    #pragma unroll
    for (int sc = 0; sc < 8; ++sc) {
        int stack = sc >> 2, c = sc & 3;
        const ushort* Msrc = stack ? MpH : MaH;
        float bv = (stack ? bpea : badj)[c * L_ * H_ + colg];   // layer 0 bias
        ushort* Gout = stack ? G1p : G1a;
        #pragma unroll
        for (int r = 0; r < 2; ++r) {
            bfrag A0 = *(const bfrag*)&Msrc[(16 * r + ml) * WPITCH + q * 8];
            bfrag A1 = *(const bfrag*)&Msrc[(16 * r + ml) * WPITCH + 32 + q * 8];
            f32x4 acc = {0.f, 0.f, 0.f, 0.f};
            acc = __builtin_amdgcn_mfma_f32_16x16x32_bf16(A0, BF[sc][0], acc, 0, 0, 0);
            acc = __builtin_amdgcn_mfma_f32_16x16x32_bf16(A1, BF[sc][1], acc, 0, 0, 0);
            #pragma unroll
            for (int j = 0; j < 4; ++j) {
                float v = acc[j] + bv;
                v = v > 0.f ? v : 0.f;
                Gout[(size_t)(m0 + 16 * r + q * 4 + j) * 256 + c * 64 + colg] = bf_rne(v);
            }
        }
    }
}

// ---------------------------------------------------------------------------
// K2: layer 1 standalone — checkpoint 0 only (cp1,2,3 embed into mix).
__global__ __launch_bounds__(256, 4) void k_layer1(
    const int*   __restrict__ cnt,
    const int*   __restrict__ cols,
    const float* __restrict__ vals,
    const float* __restrict__ inp,
    const float* __restrict__ w_in, const float* __restrict__ b_in,
    const ushort* __restrict__ WT,
    const float* __restrict__ badj, const float* __restrict__ bpea,
    ushort* __restrict__ G1a4, ushort* __restrict__ G1p4)
{
    __shared__ __align__(16) ushort MaH[32 * WPITCH];   // 4.6 KB each
    __shared__ __align__(16) ushort MpH[32 * WPITCH];
    int vb = (blockIdx.x & 7) * 82 + (blockIdx.x >> 3);   // XCD swizzle over 656
    if (vb >= 650) return;
    l1_block(vb, threadIdx.x, 3, cnt, cols, vals,
             inp, w_in, b_in, WT, badj, bpea, G1a4, G1p4, MaH, MpH);
}

// ---------------------------------------------------------------------------
// K3 (fused): LayerNorm + gf/residual + gate MLP (MFMA) + sparse gathers +
// layer-2 GEMMs + gate mix + reduce GEMM. 16 rows/block, LB(256,4).
// LN stats via per-iteration 2-float atomic accumulators (asum ping):
// phase 1 is two broadcast loads instead of a 2600-float re-reduction
// (was 82% of FETCH + a cross-XCD latency spike at dispatch start).
// Blocks >= MIXG run layer-1 for an independent checkpoint (co-scheduled).
__global__ __launch_bounds__(256, 4) void k_mix(
    const float* __restrict__ inp,
    const float* __restrict__ w_in, const float* __restrict__ b_in,
    const float* __restrict__ gconv_w, const float* __restrict__ gconv_b,
    const float* __restrict__ res_w,   const float* __restrict__ res_b,
    const float* __restrict__ cr_in, int it,
    const ushort* __restrict__ W1T, const float* __restrict__ b1,
    const ushort* __restrict__ W2T, const float* __restrict__ b2,
    const int*   __restrict__ cnt,
    const int*   __restrict__ cols,
    const float* __restrict__ vals,
    const ushort* __restrict__ G1a, const ushort* __restrict__ G1p,  // read slot
    const ushort* __restrict__ WT,      // [16][64][WPITCH]; mats 8..15 = layer1
    const float* __restrict__ badj, const float* __restrict__ bpea,
    const ushort* __restrict__ RT,      // [64][RTP] reduce_w^T bf16
    const float* __restrict__ reduce_b, // [64]
    float* __restrict__ cr,             // [M][64]
    const float* __restrict__ asum_in,  // [2] LN sums of prev iteration
    float* __restrict__ asum_out,       // [2] LN sums of this iteration
    int tt_l1,                              // embedded-L1 checkpoint time index
    ushort* __restrict__ G1a_wr, ushort* __restrict__ G1p_wr)  // embedded-L1 slot
{
    __shared__ __align__(16) ushort MtA[16 * MTP];   // 8.4 KB each
    __shared__ __align__(16) ushort MtP[16 * MTP];
    __shared__ __align__(16) ushort Gf[16 * WPITCH]; // 2.3 KB each
    __shared__ __align__(16) ushort Gr[16 * WPITCH];
    __shared__ float RES[16 * 68];                   // 4.4 KB, persists whole kernel
    __shared__ float red[8];
    int t = threadIdx.x, lane = t & 63, w = t >> 6;

    // ======== embedded layer-1 path (co-scheduled independent work) ========
    if (blockIdx.x >= MIXG) {
        int lx = blockIdx.x - MIXG;
        int vb1 = (lx & 7) * 82 + (lx >> 3);   // XCD swizzle over 656
        if (vb1 >= 650) return;
        // overlay: MtA/MtP (8.4 KB each) hold the 4.6 KB MaH/MpH tiles
        l1_block(vb1, t, tt_l1, cnt, cols, vals, inp, w_in, b_in,
                 WT, badj, bpea, G1a_wr, G1p_wr, (ushort*)MtA, (ushort*)MtP);
        return;
    }

    int vb = (blockIdx.x & 7) * 163 + (blockIdx.x >> 3);   // XCD swizzle (1304 -> 0..1303)
    if (vb >= NBLK) return;
    int m0 = vb * 16;
    int q = lane >> 4, ml = lane & 15;
    int colg = w * 16 + ml;               // this wave-lane's output column

    // ---- phase 1: LayerNorm constants — two broadcast loads ----
    float mu = 0.f, rs = 0.f;
    if (it > 0) {
        const float inv = 1.f / (float)(M_ * H_);
        float a = asum_in[0], b = asum_in[1];
        mu = a * inv;
        float var = b * inv - mu * mu;
        rs = rsqrtf(var + 1e-5f);
    }

    // ---- phase 2: gf (bf16 LDS) / residual (f32 LDS); 16 rows, 4 per wave ----
    {
        float wa = w_in[lane], wb = w_in[H_ + lane], bi = b_in[lane];
        float gw0 = gconv_w[0], gw1 = gconv_w[1], gw2 = gconv_w[2], gw3 = gconv_w[3];
        float rw0 = res_w[0],   rw1 = res_w[1],   rw2 = res_w[2],   rw3 = res_w[3];
        float gb = gconv_b[0],  rb = res_b[0];
        int t1 = (it == 0) ? 1 : (3 * it + 1);
        for (int i = 0; i < 4; ++i) {
            int r = i * 4 + w;                  // wave-uniform row
            int m = m0 + r;
            int b = m / N_, n = m % N_;
            const float* ipb = inp + ((size_t)b * T_ * N_ + n) * 2;
            float v0;
            if (it > 0) v0 = (cr_in[(size_t)m * H_ + lane] - mu) * rs;
            else        v0 = ipb[0] * wa + ipb[1] * wb + bi;
            const float* ip1 = ipb + (size_t)t1 * N_ * 2;
            const float* ip2 = ip1 + (size_t)N_ * 2;
            const float* ip3 = ip2 + (size_t)N_ * 2;
            float v1 = ip1[0] * wa + ip1[1] * wb + bi;
            float v2 = ip2[0] * wa + ip2[1] * wb + bi;
            float v3 = ip3[0] * wa + ip3[1] * wb + bi;
            Gf[r * WPITCH + lane] = bf_rne(gb + gw0 * v0 + gw1 * v1 + gw2 * v2 + gw3 * v3);
            RES[r * 68 + lane]    = rb + rw0 * v0 + rw1 * v1 + rw2 * v2 + rw3 * v3;
        }
    }
    __syncthreads();

    // ---- phase 3: gate GEMM1 = relu(Gf[16x64] @ W1 + b1) -> Gr (bf16 LDS) ----
    {
        bfrag A0 = *(const bfrag*)&Gf[ml * WPITCH + q * 8];
        bfrag A1 = *(const bfrag*)&Gf[ml * WPITCH + 32 + q * 8];
        bfrag B0 = *(const bfrag*)&W1T[(size_t)colg * WPITCH + q * 8];
        bfrag B1 = *(const bfrag*)&W1T[(size_t)colg * WPITCH + 32 + q * 8];
        f32x4 acc = {0.f, 0.f, 0.f, 0.f};
        acc = __builtin_amdgcn_mfma_f32_16x16x32_bf16(A0, B0, acc, 0, 0, 0);
        acc = __builtin_amdgcn_mfma_f32_16x16x32_bf16(A1, B1, acc, 0, 0, 0);
        float bb = b1[colg];
        #pragma unroll
        for (int j = 0; j < 4; ++j) {
            float v = acc[j] + bb;
            v = v > 0.f ? v : 0.f;
            Gr[(q * 4 + j) * WPITCH + colg] = bf_rne(v);
        }
    }
    __syncthreads();

    // ---- phase 4: gate GEMM2 -> gsv in regs (col layout == consumer layout) ----
    f32x4 gsv[4];
    {
        bfrag A0 = *(const bfrag*)&Gr[ml * WPITCH + q * 8];
        bfrag A1 = *(const bfrag*)&Gr[ml * WPITCH + 32 + q * 8];
        #pragma unroll
        for (int c = 0; c < 4; ++c) {
            bfrag B0 = *(const bfrag*)&W2T[(size_t)(c * 64 + colg) * WPITCH + q * 8];
            bfrag B1 = *(const bfrag*)&W2T[(size_t)(c * 64 + colg) * WPITCH + 32 + q * 8];
            f32x4 acc = {0.f, 0.f, 0.f, 0.f};
            acc = __builtin_amdgcn_mfma_f32_16x16x32_bf16(A0, B0, acc, 0, 0, 0);
            acc = __builtin_amdgcn_mfma_f32_16x16x32_bf16(A1, B1, acc, 0, 0, 0);
            float bb = b2[c * 64 + colg];
            #pragma unroll
            for (int j = 0; j < 4; ++j)
                gsv[c][j] = 1.f / (1.f + expf(-(acc[j] + bb)));
        }
    }
    // no barrier needed: gather writes MtA/MtP, disjoint from Gf/Gr readers

    // ---- phase 5: gather BOTH stacks; 1-ahead metadata rotation ----
    for (int pp = 0; pp < 4; pp += 2) {
        int ma = m0 + w * 4 + pp, mb = ma + 1;
        int na = ma % N_, nb = mb % N_;
        const ushort* ga = G1a + (size_t)(ma - na) * 256 + lane * 4;
        const ushort* gb = G1a + (size_t)(mb - nb) * 256 + lane * 4;
        const ushort* pa = G1p + (size_t)(ma - na) * 256 + lane * 4;
        const ushort* pb = G1p + (size_t)(mb - nb) * 256 + lane * 4;
        const int   *cA0 = cols + na * NNZCAP,        *cB0 = cols + nb * NNZCAP;
        const float *vA0 = vals + na * NNZCAP,        *vB0 = vals + nb * NNZCAP;
        const int   *cA1 = cols + (N_ + na) * NNZCAP, *cB1 = cols + (N_ + nb) * NNZCAP;
        const float *vA1 = vals + (N_ + na) * NNZCAP, *vB1 = vals + (N_ + nb) * NNZCAP;
        int jm = max(max(cnt[na], cnt[nb]), max(cnt[N_ + na], cnt[N_ + nb]));
        float4 a0 = make_float4(0.f,0.f,0.f,0.f), a1 = make_float4(0.f,0.f,0.f,0.f);
        float4 p0 = make_float4(0.f,0.f,0.f,0.f), p1 = make_float4(0.f,0.f,0.f,0.f);
        // rotation seed: iteration 0's metadata (zero-padded rows -> safe)
        int   nA00 = cA0[0], nA01 = cA0[1], nB00 = cB0[0], nB01 = cB0[1];
        int   nA10 = cA1[0], nA11 = cA1[1], nB10 = cB1[0], nB11 = cB1[1];
        float mA00 = vA0[0], mA01 = vA0[1], mB00 = vB0[0], mB01 = vB0[1];
        float mA10 = vA1[0], mA11 = vA1[1], mB10 = vB1[0], mB11 = vB1[1];
        for (int j = 0; j < jm; j += 2) {
            int   iA00 = nA00, iA01 = nA01, iB00 = nB00, iB01 = nB01;
            int   iA10 = nA10, iA11 = nA11, iB10 = nB10, iB11 = nB11;
            float uA00 = mA00, uA01 = mA01, uB00 = mB00, uB01 = mB01;
            float uA10 = mA10, uA11 = mA11, uB10 = mB10, uB11 = mB11;
            // prefetch next iteration's metadata (overlaps the gathered loads;
            // j+3 <= 65 reads pad/next-row -> valid memory, values discarded)
            nA00 = cA0[j+2]; nA01 = cA0[j+3]; nB00 = cB0[j+2]; nB01 = cB0[j+3];
            nA10 = cA1[j+2]; nA11 = cA1[j+3]; nB10 = cB1[j+2]; nB11 = cB1[j+3];
            mA00 = vA0[j+2]; mA01 = vA0[j+3]; mB00 = vB0[j+2]; mB01 = vB0[j+3];
            mA10 = vA1[j+2]; mA11 = vA1[j+3]; mB10 = vB1[j+2]; mB11 = vB1[j+3];
            fma4(a0, uA00, unpack_bf4(*(const uint2*)&ga[iA00 * 256]));
            fma4(a0, uA01, unpack_bf4(*(const uint2*)&ga[iA01 * 256]));
            fma4(a1, uB00, unpack_bf4(*(const uint2*)&gb[iB00 * 256]));
            fma4(a1, uB01, unpack_bf4(*(const uint2*)&gb[iB01 * 256]));
            fma4(p0, uA10, unpack_bf4(*(const uint2*)&pa[iA10 * 256]));
            fma4(p0, uA11, unpack_bf4(*(const uint2*)&pa[iA11 * 256]));
            fma4(p1, uB10, unpack_bf4(*(const uint2*)&pb[iB10 * 256]));
            fma4(p1, uB11, unpack_bf4(*(const uint2*)&pb[iB11 * 256]));
        }
        int row0 = w * 4 + pp;
        *(uint2*)&MtA[row0 * MTP + lane * 4]       = pack_bf4(a0);
        *(uint2*)&MtA[(row0 + 1) * MTP + lane * 4] = pack_bf4(a1);
        *(uint2*)&MtP[row0 * MTP + lane * 4]       = pack_bf4(p0);
        *(uint2*)&MtP[(row0 + 1) * MTP + lane * 4] = pack_bf4(p1);
    }
    __syncthreads();

    // ---- phase 6: 8 layer-2 GEMM stages (stack,c), MFMA, B-frag pipelined ----
    const ushort* WT1 = WT + (size_t)8 * 64 * WPITCH;
    f32x4 res[4];
    bfrag B0c = *(const bfrag*)&WT1[(size_t)colg * WPITCH + q * 8];
    bfrag B1c = *(const bfrag*)&WT1[(size_t)colg * WPITCH + 32 + q * 8];
    #pragma unroll
    for (int sc = 0; sc < 8; ++sc) {
        int stack = sc >> 2, c = sc & 3;
        bfrag B0n = B0c, B1n = B1c;
        if (sc < 7) {
            B0n = *(const bfrag*)&WT1[((size_t)(sc + 1) * 64 + colg) * WPITCH + q * 8];
            B1n = *(const bfrag*)&WT1[((size_t)(sc + 1) * 64 + colg) * WPITCH + 32 + q * 8];
        }
        const ushort* Msrc = stack ? MtP : MtA;
        float bv = (stack ? bpea : badj)[(c * L_ + 1) * H_ + colg];   // layer 1 bias
        bfrag A0 = *(const bfrag*)&Msrc[ml * MTP + c * 64 + q * 8];
        bfrag A1 = *(const bfrag*)&Msrc[ml * MTP + c * 64 + 32 + q * 8];
        f32x4 acc = {0.f, 0.f, 0.f, 0.f};
        acc = __builtin_amdgcn_mfma_f32_16x16x32_bf16(A0, B0c, acc, 0, 0, 0);
        acc = __builtin_amdgcn_mfma_f32_16x16x32_bf16(A1, B1c, acc, 0, 0, 0);
        #pragma unroll
        for (int j = 0; j < 4; ++j) {
            float v = acc[j] + bv;
            v = v > 0.f ? v : 0.f;
            if (stack == 0) res[c][j] = gsv[c][j] * v;
            else            res[c][j] += (1.f - gsv[c][j]) * v;
        }
        B0c = B0n; B1c = B1n;
    }

    // preload reduce B-frags + residual while finishing mix
    bfrag RF[8];
    #pragma unroll
    for (int kc = 0; kc < 8; ++kc)
        RF[kc] = *(const bfrag*)&RT[(size_t)colg * RTP + kc * 32 + q * 8];
    f32x4 rv;
    #pragma unroll
    for (int j = 0; j < 4; ++j)
        rv[j] = RES[(q * 4 + j) * 68 + colg];

    __syncthreads();   // all layer-2 LDS reads done -> MtA reusable
    // commit mixed result (bf16) for the reduce GEMM's A operand
    #pragma unroll
    for (int c = 0; c < 4; ++c)
        #pragma unroll
        for (int j = 0; j < 4; ++j)
            MtA[(q * 4 + j) * MTP + c * 64 + colg] = bf_rne(res[c][j]);
    __syncthreads();

    // ---- phase 7: reduce GEMM: cr = mix[16x256] @ reduce_w + bias + residual --
    f32x4 racc = {0.f, 0.f, 0.f, 0.f};
    #pragma unroll
    for (int kc = 0; kc < 8; ++kc) {
        bfrag A0 = *(const bfrag*)&MtA[ml * MTP + kc * 32 + q * 8];
        racc = __builtin_amdgcn_mfma_f32_16x16x32_bf16(A0, RF[kc], racc, 0, 0, 0);
    }

    float bi = reduce_b[colg];
    float s = 0.f, s2 = 0.f;
    #pragma unroll
    for (int j = 0; j < 4; ++j) {
        int m = m0 + q * 4 + j;
        float v = racc[j] + bi + rv[j];
        cr[(size_t)m * 64 + colg] = v;
        s += v; s2 += v * v;
    }
    // wave shuffle reduce, cross-wave via tiny LDS, then 2 atomics per block
    #pragma unroll
    for (int off = 32; off > 0; off >>= 1) {
        s  += __shfl_xor(s, off);
        s2 += __shfl_xor(s2, off);
    }
    if (lane == 0) { red[w] = s; red[4 + w] = s2; }
    __syncthreads();
    if (t == 0) atomicAdd(&asum_out[0], red[0] + red[1] + red[2] + red[3]);
    if (t == 1) atomicAdd(&asum_out[1], red[4] + red[5] + red[6] + red[7]);
}

// ---------------------------------------------------------------------------
// K5: out = relu(ocw*norm(cr) + ocb) @ olw + olb. One wave per 64 rows.
__global__ __launch_bounds__(64) void k_out(
    const float* __restrict__ cr, const float* __restrict__ asum,
    const float* __restrict__ ocw, const float* __restrict__ ocb,
    const float* __restrict__ olw, const float* __restrict__ olb,
    float* __restrict__ out) {
    int t = threadIdx.x;
    const float inv = 1.f / (float)(M_ * H_);
    float mu  = asum[0] * inv;
    float var = asum[1] * inv - mu * mu;
    float rs  = rsqrtf(var + 1e-5f);

    int m = blockIdx.x * 64 + t;          // M = 325*64 exactly
    int b = m / N_, n = m % N_;
    float cw[P_], cb[P_], acc[P_];
    #pragma unroll
    for (int p = 0; p < P_; ++p) { cw[p] = ocw[p]; cb[p] = ocb[p]; acc[p] = 0.f; }
    const float* lr = cr + (size_t)m * H_;
    for (int h4 = 0; h4 < 64; h4 += 4) {
        float4 lv4 = *(const float4*)&lr[h4];
        float4 wv4 = *(const float4*)&olw[h4];
        float lv[4] = {(lv4.x - mu) * rs, (lv4.y - mu) * rs,
                       (lv4.z - mu) * rs, (lv4.w - mu) * rs};
        float wv[4] = {wv4.x, wv4.y, wv4.z, wv4.w};
        #pragma unroll
        for (int e = 0; e < 4; ++e) {
            float lvv = lv[e], wvv = wv[e];
            #pragma unroll
            for (int p = 0; p < P_; ++p) {
                float u = cw[p] * lvv + cb[p];
                u = u > 0.f ? u : 0.f;
                acc[p] += u * wvv;
            }
        }
    }
    float ob = olb[0];
    #pragma unroll
    for (int p = 0; p < P_; ++p)
        out[(size_t)(b * P_ + p) * N_ + n] = acc[p] + ob;
}

// ---------------------------------------------------------------------------
extern "C" void kernel_launch(void* const* d_in, const int* in_sizes, int n_in,
                              void* d_out, int out_size, void* d_ws, size_t ws_size,
                              hipStream_t stream) {
    const float* inp      = (const float*)d_in[0];
    const float* adj_fwd  = (const float*)d_in[1];
    const float* pea_fwd  = (const float*)d_in[3];
    const float* w_in     = (const float*)d_in[5];
    const float* b_in     = (const float*)d_in[6];
    const float* res_w    = (const float*)d_in[7];
    const float* res_b    = (const float*)d_in[8];
    const float* gconv_w  = (const float*)d_in[9];
    const float* gconv_b  = (const float*)d_in[10];
    const float* gate1_w  = (const float*)d_in[11];
    const float* gate1_b  = (const float*)d_in[12];
    const float* gate2_w  = (const float*)d_in[13];
    const float* gate2_b  = (const float*)d_in[14];
    const float* reduce_w = (const float*)d_in[15];
    const float* reduce_b = (const float*)d_in[16];
    const float* gadj_w   = (const float*)d_in[17];
    const float* gadj_b   = (const float*)d_in[18];
    const float* gpea_w   = (const float*)d_in[19];
    const float* gpea_b   = (const float*)d_in[20];
    const float* ocw      = (const float*)d_in[21];
    const float* ocb      = (const float*)d_in[22];
    const float* olw      = (const float*)d_in[23];
    const float* olb      = (const float*)d_in[24];
    float* out = (float*)d_out;

    // workspace layout — fp32 region then bf16 buffers (~48 MB total)
    float* ws       = (float*)d_ws;
    float* cr       = ws;                              // M*64
    float* asum     = cr + (size_t)M_ * H_;            // 8 floats: [it][2]
    int*   scnt  = (int*)(asum + 8);                   // 2*325
    int*   scols = scnt + 2 * N_;                      // 2*325*64
    float* svals = (float*)(scols + 2 * N_ * NNZCAP);  // 2*325*64
    ushort* G1a4 = (ushort*)(svals + 2 * N_ * NNZCAP); // 2 slots x M*256 bf16
    ushort* G1p4 = G1a4 + 2 * (size_t)M_ * 256;        // 2 slots x M*256 bf16
    ushort* WT   = G1p4 + 2 * (size_t)M_ * 256;        // 16*64*WPITCH (16B-aligned)
    WT = (ushort*)(((uintptr_t)WT + 15) & ~(uintptr_t)15);
    ushort* RT   = WT + 16 * 64 * WPITCH;              // 64*RTP
    ushort* W1T  = RT + 64 * RTP;                      // 64*WPITCH
    ushort* W2T  = W1T + 64 * WPITCH;                  // 256*WPITCH

    // all independent prep in ONE small dispatch (also zeroes asum)
    k_setup<<<182, 256, 0, stream>>>(
        adj_fwd, pea_fwd, gadj_w, gpea_w, reduce_w,
        gate1_w, gate2_w, scnt, scols, svals, WT, RT, W1T, W2T, asum);

    // layer 1 for checkpoint 0 only (cp1,2,3 are co-scheduled inside mix)
    k_layer1<<<656, 256, 0, stream>>>(
        scnt, scols, svals, inp, w_in, b_in, WT, gadj_b, gpea_b, G1a4, G1p4);

    for (int it = 0; it < 4; ++it) {
        int slot = it & 1;
        // embed layer-1 for cp it+1 (writes slot (it+1)&1; reads slot it&1 —
        // disjoint for every it). it=3 has no successor -> no embed.
        int embed = (it < 3);
        int grid  = MIXG + (embed ? 656 : 0);
        int wrsl  = (it + 1) & 1;
        k_mix<<<grid, 256, 0, stream>>>(
            inp, w_in, b_in, gconv_w, gconv_b, res_w, res_b, cr, it,
            W1T, gate1_b, W2T, gate2_b,
            scnt, scols, svals,
            G1a4 + (size_t)slot * M_ * 256, G1p4 + (size_t)slot * M_ * 256,
            WT, gadj_b, gpea_b, RT, reduce_b, cr,
            asum + 2 * (it > 0 ? it - 1 : 0), asum + 2 * it,
            3 * (it + 1) + 3,
            G1a4 + (size_t)wrsl * M_ * 256, G1p4 + (size_t)wrsl * M_ * 256);
    }

    // final LN stats live in asum[3]
    k_out<<<N_, 64, 0, stream>>>(cr, asum + 6, ocw, ocb, olw, olb, out);
}

// Round 15
// 399.300 us; speedup vs baseline: 1.2921x; 1.2921x over previous
//
#include <hip/hip_runtime.h>
#include <hip/hip_bf16.h>
#include <math.h>

// Problem constants
#define B_    64
#define T_    13
#define N_    325
#define H_    64
#define C_    4
#define L_    2
#define S_    4
#define P_    12
#define M_    (B_*N_)      // 20800 (= 1300*16 exactly)
#define ADJLD 1300         // leading dim of combined adjacency inputs
#define NNZCAP 64          // max nonzeros per adjacency row (3% density -> mean ~10)
#define WPITCH 72          // ushort pitch for transposed W tiles (144B rows, 16B-aligned frags)
#define MTP   264          // ushort pitch for 256-wide bf16 tiles (conflict-free)
#define RTP   264          // ushort pitch for transposed reduce_w
#define NBLK  1300         // fused-mix blocks (16 rows each)
#define MIXG  1304         // mix grid (8-swizzle over 1300 + 4 dead)

typedef short bfrag __attribute__((ext_vector_type(8)));   // 8 bf16 = 4 VGPRs
typedef float f32x4 __attribute__((ext_vector_type(4)));

__device__ __forceinline__ void fma4(float4& a, float s, float4 x) {
    a.x += s * x.x; a.y += s * x.y; a.z += s * x.z; a.w += s * x.w;
}
// bf16 pack (RNE) / unpack helpers
__device__ __forceinline__ ushort bf_rne(float f) {
    unsigned u = __float_as_uint(f);
    return (ushort)((u + 0x7fffu + ((u >> 16) & 1u)) >> 16);
}
__device__ __forceinline__ uint2 pack_bf4(float4 v) {
    unsigned a = __float_as_uint(v.x), b = __float_as_uint(v.y);
    unsigned c = __float_as_uint(v.z), d = __float_as_uint(v.w);
    a = (a + 0x7fffu + ((a >> 16) & 1u)) >> 16;
    b = (b + 0x7fffu + ((b >> 16) & 1u)) >> 16;
    c = (c + 0x7fffu + ((c >> 16) & 1u)) >> 16;
    d = (d + 0x7fffu + ((d >> 16) & 1u)) >> 16;
    return make_uint2(a | (b << 16), c | (d << 16));
}
__device__ __forceinline__ float4 unpack_bf4(uint2 p) {
    return make_float4(__uint_as_float(p.x << 16),
                       __uint_as_float(p.x & 0xffff0000u),
                       __uint_as_float(p.y << 16),
                       __uint_as_float(p.y & 0xffff0000u));
}

// ---------------------------------------------------------------------------
// K_SETUP: one dispatch for all independent prep work (no g_init pass —
// layer-1 uses the rank-3 gather decomposition directly on inp).
__global__ void k_setup(
    const float* __restrict__ adj_fwd, const float* __restrict__ pea_fwd,
    const float* __restrict__ gadj_w, const float* __restrict__ gpea_w,
    const float* __restrict__ reduce_w,
    const float* __restrict__ gate1_w, const float* __restrict__ gate2_w,
    int* __restrict__ cnt, int* __restrict__ cols, float* __restrict__ vals,
    ushort* __restrict__ WT,
    ushort* __restrict__ RT, ushort* __restrict__ W1T, ushort* __restrict__ W2T)
{
    int bid = blockIdx.x, t = threadIdx.x;
    if (bid < 163) {
        // ---- sparse build: row = bid*4 + wave; padded, column-ordered ----
        int lane = t & 63, w = t >> 6;
        int row = bid * 4 + w;
        if (row >= 2 * N_) return;
        int mat = (row >= N_) ? 1 : 0;
        int n   = row - mat * N_;
        const float* A = mat ? pea_fwd : adj_fwd;
        const float* rp = A + (size_t)n * ADJLD;
        int* cw   = cols + (size_t)row * NNZCAP;
        float* vw = vals + (size_t)row * NNZCAP;
        int c = 0;
        for (int c0 = 0; c0 < 384; c0 += 64) {
            int col = c0 + lane;
            float v = (col < N_) ? rp[col] : 0.f;
            unsigned long long mmask = __ballot(v != 0.f);
            int idx = c + __popcll(mmask & ((1ull << lane) - 1ull));
            if (v != 0.f && idx < NNZCAP) { cw[idx] = col; vw[idx] = v; }
            c += __popcll(mmask);
        }
        if (c + lane < NNZCAP) { cw[c + lane] = 0; vw[c + lane] = 0.f; }
        if (lane == 0) cnt[row] = (c < NNZCAP) ? c : NNZCAP;
    } else if (bid == 163) {
        // ---- reduce_w [256][64] -> RT[64][RTP] bf16 ----
        for (int i = 0; i < 64; ++i) {
            int e = t + i * 256;              // e = k*64 + n
            int k = e >> 6, n = e & 63;
            RT[(size_t)n * RTP + k] = bf_rne(reduce_w[e]);
        }
    } else if (bid < 180) {
        // ---- W01-sum transpose: WT[mat][n][k] = W0[k][n]+W1[k][n] ----
        int mat = bid - 164;                  // 0..15
        int layer = mat >> 3, sm = mat & 7;
        int stack = sm >> 2, c = sm & 3;
        const float* w0 = (stack ? gpea_w : gadj_w) + (size_t)((c * L_ + layer) * 2) * 4096;
        const float* w1 = w0 + 4096;
        for (int i = 0; i < 16; ++i) {
            int e = t + i * 256;              // e = k*64 + n
            int k = e >> 6, n = e & 63;
            WT[((size_t)mat * 64 + n) * WPITCH + k] = bf_rne(w0[e] + w1[e]);
        }
    } else if (bid == 180) {
        for (int i = 0; i < 16; ++i) {        // gate W1 64x64
            int e = t + i * 256;
            int k = e >> 6, n = e & 63;
            W1T[(size_t)n * WPITCH + k] = bf_rne(gate1_w[e]);
        }
    } else {
        for (int i = 0; i < 64; ++i) {        // gate W2 64x256
            int e = t + i * 256;
            int k = e >> 8, n = e & 255;
            W2T[(size_t)n * WPITCH + k] = bf_rne(gate2_w[e]);
        }
    }
}

// ---------------------------------------------------------------------------
// Layer-1 block body: 32 rows, both stacks, one checkpoint.
// RANK-3 GATHER: sum_j v_j * g_init[c_j] = s0*w_in[0,:] + s1*w_in[1,:] + sv*b_in
// 8B load per nonzero; 1-ahead metadata rotation.
__device__ __forceinline__ void l1_block(
    int vb, int t, int tt,
    const int*   __restrict__ cnt,
    const int*   __restrict__ cols,
    const float* __restrict__ vals,
    const float* __restrict__ inp,
    const float* __restrict__ w_in, const float* __restrict__ b_in,
    const ushort* __restrict__ WT,
    const float* __restrict__ badj, const float* __restrict__ bpea,
    ushort* __restrict__ G1a, ushort* __restrict__ G1p,
    ushort* MaH, ushort* MpH)         // 32*WPITCH ushorts each
{
    int lane = t & 63, w = t >> 6;
    int m0 = vb * 32;
    int q = lane >> 4, ml = lane & 15;
    int colg = w * 16 + ml;               // this wave-lane's output column

    // prefetch all 16 B-fragments (overlaps gather; WT is L2-resident)
    bfrag BF[8][2];
    #pragma unroll
    for (int mat = 0; mat < 8; ++mat)
        #pragma unroll
        for (int kc = 0; kc < 2; ++kc)
            BF[mat][kc] = *(const bfrag*)&WT[((size_t)mat * 64 + colg) * WPITCH + kc * 32 + q * 8];

    // ---- rank-3 gather (1-ahead rotation) ----
    {
        int row_l  = lane & 7;
        int stackl = (lane >> 3) & 1;
        int part   = lane >> 4;
        int m = m0 + w * 8 + row_l;
        int b = m / N_;
        int n = m - b * N_;
        const float* ipb = inp + ((size_t)(b * T_ + tt) * N_) * 2;
        int rowidx = stackl * N_ + n;
        const int*   cp = cols + (size_t)rowidx * NNZCAP;
        const float* vp = vals + (size_t)rowidx * NNZCAP;
        int myc = cnt[rowidx];
        float s0 = 0.f, s1 = 0.f, sv = 0.f;
        int   cn = cp[part];
        float vn = vp[part];
        for (int j = part; j < myc; j += 4) {
            int   c = cn;
            float v = vn;
            cn = cp[j + 4];               // prefetch (pad/next-row read: discarded)
            vn = vp[j + 4];
            float2 x = *(const float2*)&ipb[(size_t)c * 2];
            s0 += v * x.x; s1 += v * x.y; sv += v;
        }
        // butterfly over part bits (lane bits 4,5)
        s0 += __shfl_xor(s0, 16); s1 += __shfl_xor(s1, 16); sv += __shfl_xor(sv, 16);
        s0 += __shfl_xor(s0, 32); s1 += __shfl_xor(s1, 32); sv += __shfl_xor(sv, 32);
        // expansion: lane = column h; rows w*8..w*8+7, both stacks
        float wa = w_in[lane], wb = w_in[H_ + lane], bi = b_in[lane];
        #pragma unroll
        for (int r = 0; r < 8; ++r) {
            float a0 = __shfl(s0, r),     a1 = __shfl(s1, r),     av = __shfl(sv, r);
            float p0 = __shfl(s0, 8 + r), p1 = __shfl(s1, 8 + r), pv = __shfl(sv, 8 + r);
            MaH[(w * 8 + r) * WPITCH + lane] = bf_rne(a0 * wa + a1 * wb + av * bi);
            MpH[(w * 8 + r) * WPITCH + lane] = bf_rne(p0 * wa + p1 * wb + pv * bi);
        }
    }
    __syncthreads();

    // ---- 8 stages x 2 rowgroups, MFMA; C-layout col=ml, row=q*4+j ----
    #pragma unroll
    for (int sc = 0; sc < 8; ++sc) {
        int stack = sc >> 2, c = sc & 3;
        const ushort* Msrc = stack ? MpH : MaH;
        float bv = (stack ? bpea : badj)[c * L_ * H_ + colg];   // layer 0 bias
        ushort* Gout = stack ? G1p : G1a;
        #pragma unroll
        for (int r = 0; r < 2; ++r) {
            bfrag A0 = *(const bfrag*)&Msrc[(16 * r + ml) * WPITCH + q * 8];
            bfrag A1 = *(const bfrag*)&Msrc[(16 * r + ml) * WPITCH + 32 + q * 8];
            f32x4 acc = {0.f, 0.f, 0.f, 0.f};
            acc = __builtin_amdgcn_mfma_f32_16x16x32_bf16(A0, BF[sc][0], acc, 0, 0, 0);
            acc = __builtin_amdgcn_mfma_f32_16x16x32_bf16(A1, BF[sc][1], acc, 0, 0, 0);
            #pragma unroll
            for (int j = 0; j < 4; ++j) {
                float v = acc[j] + bv;
                v = v > 0.f ? v : 0.f;
                Gout[(size_t)(m0 + 16 * r + q * 4 + j) * 256 + c * 64 + colg] = bf_rne(v);
            }
        }
    }
}

// ---------------------------------------------------------------------------
// K2: layer 1 standalone — checkpoint 0 only (cp1,2,3 embed into mix).
__global__ __launch_bounds__(256, 4) void k_layer1(
    const int*   __restrict__ cnt,
    const int*   __restrict__ cols,
    const float* __restrict__ vals,
    const float* __restrict__ inp,
    const float* __restrict__ w_in, const float* __restrict__ b_in,
    const ushort* __restrict__ WT,
    const float* __restrict__ badj, const float* __restrict__ bpea,
    ushort* __restrict__ G1a4, ushort* __restrict__ G1p4)
{
    __shared__ __align__(16) ushort MaH[32 * WPITCH];   // 4.6 KB each
    __shared__ __align__(16) ushort MpH[32 * WPITCH];
    int vb = (blockIdx.x & 7) * 82 + (blockIdx.x >> 3);   // XCD swizzle over 656
    if (vb >= 650) return;
    l1_block(vb, threadIdx.x, 3, cnt, cols, vals,
             inp, w_in, b_in, WT, badj, bpea, G1a4, G1p4, MaH, MpH);
}

// ---------------------------------------------------------------------------
// K3 (fused): LayerNorm + gf/residual + gate MLP (MFMA) + sparse gathers +
// layer-2 GEMMs + gate mix + reduce GEMM + partials. 16 rows/block, LB(256,4)
// (proven: every occupancy-raise attempt at this kernel spilled — r7, r10;
//  atomic-scalarized LN regressed 45% — r14: cross-XCD atomic serialization).
// Partials PING-PONG (pin != pout) kills the same-dispatch read/write race.
// Blocks >= MIXG run layer-1 for an independent checkpoint (co-scheduled).
__global__ __launch_bounds__(256, 4) void k_mix(
    const float* __restrict__ inp,
    const float* __restrict__ w_in, const float* __restrict__ b_in,
    const float* __restrict__ gconv_w, const float* __restrict__ gconv_b,
    const float* __restrict__ res_w,   const float* __restrict__ res_b,
    const float* __restrict__ cr_in, int it,
    const ushort* __restrict__ W1T, const float* __restrict__ b1,
    const ushort* __restrict__ W2T, const float* __restrict__ b2,
    const int*   __restrict__ cnt,
    const int*   __restrict__ cols,
    const float* __restrict__ vals,
    const ushort* __restrict__ G1a, const ushort* __restrict__ G1p,  // read slot
    const ushort* __restrict__ WT,      // [16][64][WPITCH]; mats 8..15 = layer1
    const float* __restrict__ badj, const float* __restrict__ bpea,
    const ushort* __restrict__ RT,      // [64][RTP] reduce_w^T bf16
    const float* __restrict__ reduce_b, // [64]
    float* __restrict__ cr,             // [M][64]
    const float* __restrict__ partials_in,   // read buffer (prev iteration)
    float* __restrict__ partials_out,        // write buffer (this iteration)
    int tt_l1,                              // embedded-L1 checkpoint time index
    ushort* __restrict__ G1a_wr, ushort* __restrict__ G1p_wr)  // embedded-L1 slot
{
    __shared__ __align__(16) ushort MtA[16 * MTP];   // 8.4 KB each
    __shared__ __align__(16) ushort MtP[16 * MTP];
    __shared__ __align__(16) ushort Gf[16 * WPITCH]; // 2.3 KB each
    __shared__ __align__(16) ushort Gr[16 * WPITCH];
    __shared__ float RES[16 * 68];                   // 4.4 KB, persists whole kernel
    __shared__ float red[8];
    int t = threadIdx.x, lane = t & 63, w = t >> 6;

    // ======== embedded layer-1 path (co-scheduled independent work) ========
    if (blockIdx.x >= MIXG) {
        int lx = blockIdx.x - MIXG;
        int vb1 = (lx & 7) * 82 + (lx >> 3);   // XCD swizzle over 656
        if (vb1 >= 650) return;
        // overlay: MtA/MtP (8.4 KB each) hold the 4.6 KB MaH/MpH tiles
        l1_block(vb1, t, tt_l1, cnt, cols, vals, inp, w_in, b_in,
                 WT, badj, bpea, G1a_wr, G1p_wr, (ushort*)MtA, (ushort*)MtP);
        return;
    }

    int vb = (blockIdx.x & 7) * 163 + (blockIdx.x >> 3);   // XCD swizzle (1304 -> 0..1303)
    if (vb >= NBLK) return;
    int m0 = vb * 16;
    int q = lane >> 4, ml = lane & 15;
    int colg = w * 16 + ml;               // this wave-lane's output column

    // ---- phase 1: LayerNorm constants (wave shuffle reduce, 1 barrier) ----
    float mu = 0.f, rs = 0.f;
    if (it > 0) {
        float a = 0.f, b = 0.f;
        for (int i = t; i < NBLK; i += 256) { a += partials_in[i]; b += partials_in[NBLK + i]; }
        #pragma unroll
        for (int off = 32; off > 0; off >>= 1) {
            a += __shfl_xor(a, off);
            b += __shfl_xor(b, off);
        }
        if (lane == 0) { red[w] = a; red[4 + w] = b; }
        __syncthreads();
        a = red[0] + red[1] + red[2] + red[3];
        b = red[4] + red[5] + red[6] + red[7];
        const float inv = 1.f / (float)(M_ * H_);
        mu = a * inv;
        float var = b * inv - mu * mu;
        rs = rsqrtf(var + 1e-5f);
    }

    // ---- phase 2: gf (bf16 LDS) / residual (f32 LDS); 16 rows, 4 per wave ----
    {
        float wa = w_in[lane], wb = w_in[H_ + lane], bi = b_in[lane];
        float gw0 = gconv_w[0], gw1 = gconv_w[1], gw2 = gconv_w[2], gw3 = gconv_w[3];
        float rw0 = res_w[0],   rw1 = res_w[1],   rw2 = res_w[2],   rw3 = res_w[3];
        float gb = gconv_b[0],  rb = res_b[0];
        int t1 = (it == 0) ? 1 : (3 * it + 1);
        for (int i = 0; i < 4; ++i) {
            int r = i * 4 + w;                  // wave-uniform row
            int m = m0 + r;
            int b = m / N_, n = m % N_;
            const float* ipb = inp + ((size_t)b * T_ * N_ + n) * 2;
            float v0;
            if (it > 0) v0 = (cr_in[(size_t)m * H_ + lane] - mu) * rs;
            else        v0 = ipb[0] * wa + ipb[1] * wb + bi;
            const float* ip1 = ipb + (size_t)t1 * N_ * 2;
            const float* ip2 = ip1 + (size_t)N_ * 2;
            const float* ip3 = ip2 + (size_t)N_ * 2;
            float v1 = ip1[0] * wa + ip1[1] * wb + bi;
            float v2 = ip2[0] * wa + ip2[1] * wb + bi;
            float v3 = ip3[0] * wa + ip3[1] * wb + bi;
            Gf[r * WPITCH + lane] = bf_rne(gb + gw0 * v0 + gw1 * v1 + gw2 * v2 + gw3 * v3);
            RES[r * 68 + lane]    = rb + rw0 * v0 + rw1 * v1 + rw2 * v2 + rw3 * v3;
        }
    }
    __syncthreads();

    // ---- phase 3: gate GEMM1 = relu(Gf[16x64] @ W1 + b1) -> Gr (bf16 LDS) ----
    {
        bfrag A0 = *(const bfrag*)&Gf[ml * WPITCH + q * 8];
        bfrag A1 = *(const bfrag*)&Gf[ml * WPITCH + 32 + q * 8];
        bfrag B0 = *(const bfrag*)&W1T[(size_t)colg * WPITCH + q * 8];
        bfrag B1 = *(const bfrag*)&W1T[(size_t)colg * WPITCH + 32 + q * 8];
        f32x4 acc = {0.f, 0.f, 0.f, 0.f};
        acc = __builtin_amdgcn_mfma_f32_16x16x32_bf16(A0, B0, acc, 0, 0, 0);
        acc = __builtin_amdgcn_mfma_f32_16x16x32_bf16(A1, B1, acc, 0, 0, 0);
        float bb = b1[colg];
        #pragma unroll
        for (int j = 0; j < 4; ++j) {
            float v = acc[j] + bb;
            v = v > 0.f ? v : 0.f;
            Gr[(q * 4 + j) * WPITCH + colg] = bf_rne(v);
        }
    }
    __syncthreads();

    // ---- phase 4: gate GEMM2 -> gsv in regs (col layout == consumer layout) ----
    f32x4 gsv[4];
    {
        bfrag A0 = *(const bfrag*)&Gr[ml * WPITCH + q * 8];
        bfrag A1 = *(const bfrag*)&Gr[ml * WPITCH + 32 + q * 8];
        #pragma unroll
        for (int c = 0; c < 4; ++c) {
            bfrag B0 = *(const bfrag*)&W2T[(size_t)(c * 64 + colg) * WPITCH + q * 8];
            bfrag B1 = *(const bfrag*)&W2T[(size_t)(c * 64 + colg) * WPITCH + 32 + q * 8];
            f32x4 acc = {0.f, 0.f, 0.f, 0.f};
            acc = __builtin_amdgcn_mfma_f32_16x16x32_bf16(A0, B0, acc, 0, 0, 0);
            acc = __builtin_amdgcn_mfma_f32_16x16x32_bf16(A1, B1, acc, 0, 0, 0);
            float bb = b2[c * 64 + colg];
            #pragma unroll
            for (int j = 0; j < 4; ++j)
                gsv[c][j] = 1.f / (1.f + expf(-(acc[j] + bb)));
        }
    }
    // no barrier needed: gather writes MtA/MtP, disjoint from Gf/Gr readers

    // ---- phase 5: gather BOTH stacks; 1-ahead metadata rotation ----
    for (int pp = 0; pp < 4; pp += 2) {
        int ma = m0 + w * 4 + pp, mb = ma + 1;
        int na = ma % N_, nb = mb % N_;
        const ushort* ga = G1a + (size_t)(ma - na) * 256 + lane * 4;
        const ushort* gb = G1a + (size_t)(mb - nb) * 256 + lane * 4;
        const ushort* pa = G1p + (size_t)(ma - na) * 256 + lane * 4;
        const ushort* pb = G1p + (size_t)(mb - nb) * 256 + lane * 4;
        const int   *cA0 = cols + na * NNZCAP,        *cB0 = cols + nb * NNZCAP;
        const float *vA0 = vals + na * NNZCAP,        *vB0 = vals + nb * NNZCAP;
        const int   *cA1 = cols + (N_ + na) * NNZCAP, *cB1 = cols + (N_ + nb) * NNZCAP;
        const float *vA1 = vals + (N_ + na) * NNZCAP, *vB1 = vals + (N_ + nb) * NNZCAP;
        int jm = max(max(cnt[na], cnt[nb]), max(cnt[N_ + na], cnt[N_ + nb]));
        float4 a0 = make_float4(0.f,0.f,0.f,0.f), a1 = make_float4(0.f,0.f,0.f,0.f);
        float4 p0 = make_float4(0.f,0.f,0.f,0.f), p1 = make_float4(0.f,0.f,0.f,0.f);
        // rotation seed: iteration 0's metadata (zero-padded rows -> safe)
        int   nA00 = cA0[0], nA01 = cA0[1], nB00 = cB0[0], nB01 = cB0[1];
        int   nA10 = cA1[0], nA11 = cA1[1], nB10 = cB1[0], nB11 = cB1[1];
        float mA00 = vA0[0], mA01 = vA0[1], mB00 = vB0[0], mB01 = vB0[1];
        float mA10 = vA1[0], mA11 = vA1[1], mB10 = vB1[0], mB11 = vB1[1];
        for (int j = 0; j < jm; j += 2) {
            int   iA00 = nA00, iA01 = nA01, iB00 = nB00, iB01 = nB01;
            int   iA10 = nA10, iA11 = nA11, iB10 = nB10, iB11 = nB11;
            float uA00 = mA00, uA01 = mA01, uB00 = mB00, uB01 = mB01;
            float uA10 = mA10, uA11 = mA11, uB10 = mB10, uB11 = mB11;
            // prefetch next iteration's metadata (overlaps the gathered loads;
            // j+3 <= 65 reads pad/next-row -> valid memory, values discarded)
            nA00 = cA0[j+2]; nA01 = cA0[j+3]; nB00 = cB0[j+2]; nB01 = cB0[j+3];
            nA10 = cA1[j+2]; nA11 = cA1[j+3]; nB10 = cB1[j+2]; nB11 = cB1[j+3];
            mA00 = vA0[j+2]; mA01 = vA0[j+3]; mB00 = vB0[j+2]; mB01 = vB0[j+3];
            mA10 = vA1[j+2]; mA11 = vA1[j+3]; mB10 = vB1[j+2]; mB11 = vB1[j+3];
            fma4(a0, uA00, unpack_bf4(*(const uint2*)&ga[iA00 * 256]));
            fma4(a0, uA01, unpack_bf4(*(const uint2*)&ga[iA01 * 256]));
            fma4(a1, uB00, unpack_bf4(*(const uint2*)&gb[iB00 * 256]));
            fma4(a1, uB01, unpack_bf4(*(const uint2*)&gb[iB01 * 256]));
            fma4(p0, uA10, unpack_bf4(*(const uint2*)&pa[iA10 * 256]));
            fma4(p0, uA11, unpack_bf4(*(const uint2*)&pa[iA11 * 256]));
            fma4(p1, uB10, unpack_bf4(*(const uint2*)&pb[iB10 * 256]));
            fma4(p1, uB11, unpack_bf4(*(const uint2*)&pb[iB11 * 256]));
        }
        int row0 = w * 4 + pp;
        *(uint2*)&MtA[row0 * MTP + lane * 4]       = pack_bf4(a0);
        *(uint2*)&MtA[(row0 + 1) * MTP + lane * 4] = pack_bf4(a1);
        *(uint2*)&MtP[row0 * MTP + lane * 4]       = pack_bf4(p0);
        *(uint2*)&MtP[(row0 + 1) * MTP + lane * 4] = pack_bf4(p1);
    }
    __syncthreads();

    // ---- phase 6: 8 layer-2 GEMM stages (stack,c), MFMA, B-frag pipelined ----
    const ushort* WT1 = WT + (size_t)8 * 64 * WPITCH;
    f32x4 res[4];
    bfrag B0c = *(const bfrag*)&WT1[(size_t)colg * WPITCH + q * 8];
    bfrag B1c = *(const bfrag*)&WT1[(size_t)colg * WPITCH + 32 + q * 8];
    #pragma unroll
    for (int sc = 0; sc < 8; ++sc) {
        int stack = sc >> 2, c = sc & 3;
        bfrag B0n = B0c, B1n = B1c;
        if (sc < 7) {
            B0n = *(const bfrag*)&WT1[((size_t)(sc + 1) * 64 + colg) * WPITCH + q * 8];
            B1n = *(const bfrag*)&WT1[((size_t)(sc + 1) * 64 + colg) * WPITCH + 32 + q * 8];
        }
        const ushort* Msrc = stack ? MtP : MtA;
        float bv = (stack ? bpea : badj)[(c * L_ + 1) * H_ + colg];   // layer 1 bias
        bfrag A0 = *(const bfrag*)&Msrc[ml * MTP + c * 64 + q * 8];
        bfrag A1 = *(const bfrag*)&Msrc[ml * MTP + c * 64 + 32 + q * 8];
        f32x4 acc = {0.f, 0.f, 0.f, 0.f};
        acc = __builtin_amdgcn_mfma_f32_16x16x32_bf16(A0, B0c, acc, 0, 0, 0);
        acc = __builtin_amdgcn_mfma_f32_16x16x32_bf16(A1, B1c, acc, 0, 0, 0);
        #pragma unroll
        for (int j = 0; j < 4; ++j) {
            float v = acc[j] + bv;
            v = v > 0.f ? v : 0.f;
            if (stack == 0) res[c][j] = gsv[c][j] * v;
            else            res[c][j] += (1.f - gsv[c][j]) * v;
        }
        B0c = B0n; B1c = B1n;
    }

    // preload reduce B-frags + residual while finishing mix
    bfrag RF[8];
    #pragma unroll
    for (int kc = 0; kc < 8; ++kc)
        RF[kc] = *(const bfrag*)&RT[(size_t)colg * RTP + kc * 32 + q * 8];
    f32x4 rv;
    #pragma unroll
    for (int j = 0; j < 4; ++j)
        rv[j] = RES[(q * 4 + j) * 68 + colg];

    __syncthreads();   // all layer-2 LDS reads done -> MtA reusable
    // commit mixed result (bf16) for the reduce GEMM's A operand
    #pragma unroll
    for (int c = 0; c < 4; ++c)
        #pragma unroll
        for (int j = 0; j < 4; ++j)
            MtA[(q * 4 + j) * MTP + c * 64 + colg] = bf_rne(res[c][j]);
    __syncthreads();

    // ---- phase 7: reduce GEMM: cr = mix[16x256] @ reduce_w + bias + residual --
    f32x4 racc = {0.f, 0.f, 0.f, 0.f};
    #pragma unroll
    for (int kc = 0; kc < 8; ++kc) {
        bfrag A0 = *(const bfrag*)&MtA[ml * MTP + kc * 32 + q * 8];
        racc = __builtin_amdgcn_mfma_f32_16x16x32_bf16(A0, RF[kc], racc, 0, 0, 0);
    }

    float bi = reduce_b[colg];
    float s = 0.f, s2 = 0.f;
    #pragma unroll
    for (int j = 0; j < 4; ++j) {
        int m = m0 + q * 4 + j;
        float v = racc[j] + bi + rv[j];
        cr[(size_t)m * 64 + colg] = v;
        s += v; s2 += v * v;
    }
    // wave shuffle reduce, then cross-wave via tiny LDS
    #pragma unroll
    for (int off = 32; off > 0; off >>= 1) {
        s  += __shfl_xor(s, off);
        s2 += __shfl_xor(s2, off);
    }
    if (lane == 0) { red[w] = s; red[4 + w] = s2; }
    __syncthreads();
    if (t == 0) partials_out[vb]        = red[0] + red[1] + red[2] + red[3];
    if (t == 1) partials_out[NBLK + vb] = red[4] + red[5] + red[6] + red[7];
}

// ---------------------------------------------------------------------------
// K5: out = relu(ocw*norm(cr) + ocb) @ olw + olb. One wave per 64 rows.
__global__ __launch_bounds__(64) void k_out(
    const float* __restrict__ cr, const float* __restrict__ partials,
    const float* __restrict__ ocw, const float* __restrict__ ocb,
    const float* __restrict__ olw, const float* __restrict__ olb,
    float* __restrict__ out) {
    int t = threadIdx.x;
    float a = 0.f, b2s = 0.f;
    for (int i = t; i < NBLK; i += 64) { a += partials[i]; b2s += partials[NBLK + i]; }
    #pragma unroll
    for (int off = 32; off > 0; off >>= 1) {
        a   += __shfl_xor(a, off);
        b2s += __shfl_xor(b2s, off);
    }
    const float inv = 1.f / (float)(M_ * H_);
    float mu  = a * inv;
    float var = b2s * inv - mu * mu;
    float rs  = rsqrtf(var + 1e-5f);

    int m = blockIdx.x * 64 + t;          // M = 325*64 exactly
    int b = m / N_, n = m % N_;
    float cw[P_], cb[P_], acc[P_];
    #pragma unroll
    for (int p = 0; p < P_; ++p) { cw[p] = ocw[p]; cb[p] = ocb[p]; acc[p] = 0.f; }
    const float* lr = cr + (size_t)m * H_;
    for (int h4 = 0; h4 < 64; h4 += 4) {
        float4 lv4 = *(const float4*)&lr[h4];
        float4 wv4 = *(const float4*)&olw[h4];
        float lv[4] = {(lv4.x - mu) * rs, (lv4.y - mu) * rs,
                       (lv4.z - mu) * rs, (lv4.w - mu) * rs};
        float wv[4] = {wv4.x, wv4.y, wv4.z, wv4.w};
        #pragma unroll
        for (int e = 0; e < 4; ++e) {
            float lvv = lv[e], wvv = wv[e];
            #pragma unroll
            for (int p = 0; p < P_; ++p) {
                float u = cw[p] * lvv + cb[p];
                u = u > 0.f ? u : 0.f;
                acc[p] += u * wvv;
            }
        }
    }
    float ob = olb[0];
    #pragma unroll
    for (int p = 0; p < P_; ++p)
        out[(size_t)(b * P_ + p) * N_ + n] = acc[p] + ob;
}

// ---------------------------------------------------------------------------
extern "C" void kernel_launch(void* const* d_in, const int* in_sizes, int n_in,
                              void* d_out, int out_size, void* d_ws, size_t ws_size,
                              hipStream_t stream) {
    const float* inp      = (const float*)d_in[0];
    const float* adj_fwd  = (const float*)d_in[1];
    const float* pea_fwd  = (const float*)d_in[3];
    const float* w_in     = (const float*)d_in[5];
    const float* b_in     = (const float*)d_in[6];
    const float* res_w    = (const float*)d_in[7];
    const float* res_b    = (const float*)d_in[8];
    const float* gconv_w  = (const float*)d_in[9];
    const float* gconv_b  = (const float*)d_in[10];
    const float* gate1_w  = (const float*)d_in[11];
    const float* gate1_b  = (const float*)d_in[12];
    const float* gate2_w  = (const float*)d_in[13];
    const float* gate2_b  = (const float*)d_in[14];
    const float* reduce_w = (const float*)d_in[15];
    const float* reduce_b = (const float*)d_in[16];
    const float* gadj_w   = (const float*)d_in[17];
    const float* gadj_b   = (const float*)d_in[18];
    const float* gpea_w   = (const float*)d_in[19];
    const float* gpea_b   = (const float*)d_in[20];
    const float* ocw      = (const float*)d_in[21];
    const float* ocb      = (const float*)d_in[22];
    const float* olw      = (const float*)d_in[23];
    const float* olb      = (const float*)d_in[24];
    float* out = (float*)d_out;

    // workspace layout — fp32 region then bf16 buffers (~48 MB total)
    float* ws       = (float*)d_ws;
    float* cr       = ws;                              // M*64
    float* pb0      = cr + (size_t)M_ * H_;            // 2*NBLK
    float* pb1      = pb0 + 2 * NBLK;                  // 2*NBLK
    int*   scnt  = (int*)(pb1 + 2 * NBLK);             // 2*325
    int*   scols = scnt + 2 * N_;                      // 2*325*64
    float* svals = (float*)(scols + 2 * N_ * NNZCAP);  // 2*325*64
    ushort* G1a4 = (ushort*)(svals + 2 * N_ * NNZCAP); // 2 slots x M*256 bf16
    ushort* G1p4 = G1a4 + 2 * (size_t)M_ * 256;        // 2 slots x M*256 bf16
    ushort* WT   = G1p4 + 2 * (size_t)M_ * 256;        // 16*64*WPITCH (16B-aligned)
    WT = (ushort*)(((uintptr_t)WT + 15) & ~(uintptr_t)15);
    ushort* RT   = WT + 16 * 64 * WPITCH;              // 64*RTP
    ushort* W1T  = RT + 64 * RTP;                      // 64*WPITCH
    ushort* W2T  = W1T + 64 * WPITCH;                  // 256*WPITCH

    // all independent prep in ONE small dispatch (no g_init pass needed)
    k_setup<<<182, 256, 0, stream>>>(
        adj_fwd, pea_fwd, gadj_w, gpea_w, reduce_w,
        gate1_w, gate2_w, scnt, scols, svals, WT, RT, W1T, W2T);

    // layer 1 for checkpoint 0 only (cp1,2,3 are co-scheduled inside mix)
    k_layer1<<<656, 256, 0, stream>>>(
        scnt, scols, svals, inp, w_in, b_in, WT, gadj_b, gpea_b, G1a4, G1p4);

    for (int it = 0; it < 4; ++it) {
        int slot = it & 1;
        // embed layer-1 for cp it+1 (writes slot (it+1)&1; reads slot it&1 —
        // disjoint for every it). it=3 has no successor -> no embed.
        int embed = (it < 3);
        int grid  = MIXG + (embed ? 656 : 0);
        int wrsl  = (it + 1) & 1;
        // partials ping-pong: it reads pb[(it-1)&1], writes pb[it&1]
        const float* pin = (it & 1) ? pb0 : pb1;
        float* pout      = (it & 1) ? pb1 : pb0;
        k_mix<<<grid, 256, 0, stream>>>(
            inp, w_in, b_in, gconv_w, gconv_b, res_w, res_b, cr, it,
            W1T, gate1_b, W2T, gate2_b,
            scnt, scols, svals,
            G1a4 + (size_t)slot * M_ * 256, G1p4 + (size_t)slot * M_ * 256,
            WT, gadj_b, gpea_b, RT, reduce_b, cr, pin, pout,
            3 * (it + 1) + 3,
            G1a4 + (size_t)wrsl * M_ * 256, G1p4 + (size_t)wrsl * M_ * 256);
    }

    // it=3 wrote pb[3&1] = pb1
    k_out<<<N_, 64, 0, stream>>>(cr, pb1, ocw, ocb, olw, olb, out);
}